// Round 5
// baseline (104.517 us; speedup 1.0000x reference)
//
#include <hip/hip_runtime.h>
#include <math.h>

// Chamfer distance, B=4, N=M=8192, D=3, fp32.
// Dot-product formulation: d^2/2 = 0.5|q|^2 + 0.5|r|^2 - q.r
// => min_r d^2  <=>  max_r t,  t = q.r - 0.5|r|^2.
// Inner loop: 3 fma + 0.5 v_max3 per pair = 3.5 VALU insts/pair.
//
// DS roofline (round-3/4 lesson): each pair consumes 16B/NPT of LDS ref
// data. NPT=4 -> 2.15 GB / 256 CU / ~85 B/cyc = 41 us (matched measured
// 44.7). NPT=8 halves DS demand below the VALU floor (~25 us) -> VALU-bound,
// PROVIDED occupancy stays at 8 waves/SIMD: grid must stay at 2048 blocks,
// hence MSPLIT=64 (round 4's regression was 1024 blocks = 4 waves/SIMD).
//
// No atomics / no sentinel memset: each (query, slice) partial goes to its
// own ws slot [2B][MSPLIT][NQ] (16 MB, every slot written deterministically);
// the NN kernel also zeroes out[0] (stream-ordered before reduce). Graph is
// 2 nodes instead of 4. Fallback to the proven atomic 4-node path if ws_size
// is too small (branch on call-invariant ws_size: capture-safe).

constexpr int TPB = 256;   // threads per block

template <int NPT, int MT, bool DIRECT>
__global__ __launch_bounds__(TPB, 8) void chamfer_nn(
    const float* __restrict__ A,          // [B, N, 3] input cloud
    const float* __restrict__ Bp,         // [B, M, 3] target cloud
    float* __restrict__ wsD,              // [2B][gridDim.y][NQ] (DIRECT)
    unsigned int* __restrict__ minA,      // [B, N] sentinel path (!DIRECT)
    unsigned int* __restrict__ minB,      // [B, M] sentinel path (!DIRECT)
    int N, int M, int B, float* __restrict__ out)
{
    const int bz  = blockIdx.z;
    const int b   = bz % B;
    const int dir = bz / B;               // 0: query=A ref=B, 1: query=B ref=A

    if (DIRECT && bz == 0 && blockIdx.x == 0 && blockIdx.y == 0 &&
        threadIdx.x == 0) {
        *out = 0.0f;                      // reduce runs stream-after
    }

    const float* Q = dir ? Bp : A;
    const float* R = dir ? A  : Bp;
    const int NQ = dir ? M : N;
    const int NR = dir ? N : M;
    const int mSlice = NR / gridDim.y;

    const int tid    = threadIdx.x;
    const int nBase  = blockIdx.x * (TPB * NPT);
    const int mStart = blockIdx.y * mSlice;

    const float* qb = Q + (size_t)b * NQ * 3;
    const float* rb = R + (size_t)b * NR * 3;

    float qx[NPT], qy[NPT], qz[NPT], cq[NPT], dmax[NPT];
#pragma unroll
    for (int k = 0; k < NPT; ++k) {
        const int n = nBase + tid + k * TPB;
        qx[k] = qb[n * 3 + 0];
        qy[k] = qb[n * 3 + 1];
        qz[k] = qb[n * 3 + 2];
        cq[k] = 0.5f * fmaf(qz[k], qz[k], fmaf(qy[k], qy[k], qx[k] * qx[k]));
        dmax[k] = -3.4e38f;
    }

    __shared__ float4 tgt[MT];  // {x, y, z, -0.5*|r|^2}

    for (int m0 = mStart; m0 < mStart + mSlice; m0 += MT) {
        __syncthreads();  // protect previous tile's readers
        if (tid < MT) {
            const float* src = rb + (size_t)(m0 + tid) * 3;
            const float rx = src[0];
            const float ry = src[1];
            const float rz = src[2];
            const float negc = -0.5f * fmaf(rz, rz, fmaf(ry, ry, rx * rx));
            tgt[tid] = make_float4(rx, ry, rz, negc);
        }
        __syncthreads();

#pragma unroll 2
        for (int j = 0; j < MT; j += 4) {
            // 4 refs = 4 broadcast ds_read_b128 (uniform addr -> conflict-
            // free), amortized over NPT queries: 16B/NPT DS bytes per pair.
            const float4 r0 = tgt[j + 0];
            const float4 r1 = tgt[j + 1];
            const float4 r2 = tgt[j + 2];
            const float4 r3 = tgt[j + 3];
#pragma unroll
            for (int k = 0; k < NPT; ++k) {
                const float t0 = fmaf(qz[k], r0.z, fmaf(qy[k], r0.y, fmaf(qx[k], r0.x, r0.w)));
                const float t1 = fmaf(qz[k], r1.z, fmaf(qy[k], r1.y, fmaf(qx[k], r1.x, r1.w)));
                const float t2 = fmaf(qz[k], r2.z, fmaf(qy[k], r2.y, fmaf(qx[k], r2.x, r2.w)));
                const float t3 = fmaf(qz[k], r3.z, fmaf(qy[k], r3.y, fmaf(qx[k], r3.x, r3.w)));
                // nested fmaxf pairs -> 2x v_max3_f32
                const float m01 = fmaxf(fmaxf(t0, t1), t2);
                dmax[k] = fmaxf(fmaxf(dmax[k], m01), t3);
            }
        }
    }

#pragma unroll
    for (int k = 0; k < NPT; ++k) {
        const int n = nBase + tid + k * TPB;
        const float sval = fmaxf(cq[k] - dmax[k], 0.0f);  // d^2/2, clamped
        if (DIRECT) {
            wsD[((size_t)bz * gridDim.y + blockIdx.y) * NQ + n] = sval;
        } else {
            // d2>=0 so f32 bit order == float order under uint min.
            unsigned int* om = dir ? minB : minA;
            atomicMin(&om[(size_t)b * NQ + n], __float_as_uint(sval));
        }
    }
}

// Direct-path reduce: min over S slices per query slot, then sqrt+mean+sum.
__global__ __launch_bounds__(256) void reduce_direct(
    const float* __restrict__ wsD, int NQ, int S, int B,
    float invN, float invM, float* __restrict__ out)
{
    const int total = 2 * B * NQ;
    float s = 0.0f;
    for (int i = blockIdx.x * blockDim.x + threadIdx.x; i < total;
         i += gridDim.x * blockDim.x) {
        const int bz = i / NQ;            // NQ is pow2 -> shifts
        const int n  = i - bz * NQ;
        const float* p = wsD + ((size_t)bz * S) * NQ + n;
        float v0 = p[0 * (size_t)NQ], v1 = p[1 * (size_t)NQ];
        float v2 = p[2 * (size_t)NQ], v3 = p[3 * (size_t)NQ];
        for (int sl = 4; sl < S; sl += 4) {
            v0 = fminf(v0, p[(size_t)(sl + 0) * NQ]);
            v1 = fminf(v1, p[(size_t)(sl + 1) * NQ]);
            v2 = fminf(v2, p[(size_t)(sl + 2) * NQ]);
            v3 = fminf(v3, p[(size_t)(sl + 3) * NQ]);
        }
        const float v = fminf(fminf(v0, v1), fminf(v2, v3));
        const float scale = (bz < B) ? invN : invM;
        s += sqrtf(2.0f * fmaxf(v, 0.0f)) * scale;
    }
#pragma unroll
    for (int off = 32; off > 0; off >>= 1) s += __shfl_down(s, off, 64);
    __shared__ float wsum[4];
    const int lane = threadIdx.x & 63;
    const int wid  = threadIdx.x >> 6;
    if (lane == 0) wsum[wid] = s;
    __syncthreads();
    if (threadIdx.x == 0) {
        atomicAdd(out, wsum[0] + wsum[1] + wsum[2] + wsum[3]);
    }
}

// Sentinel-path reduce (fallback).
__global__ __launch_bounds__(256) void chamfer_reduce(
    const unsigned int* __restrict__ mins, int nA, int nTotal,
    float scaleA, float scaleB, float* __restrict__ out)
{
    float s = 0.0f;
    for (int i = blockIdx.x * blockDim.x + threadIdx.x; i < nTotal;
         i += gridDim.x * blockDim.x) {
        const float half_d2 = __uint_as_float(mins[i]);
        s += sqrtf(2.0f * half_d2) * (i < nA ? scaleA : scaleB);
    }
#pragma unroll
    for (int off = 32; off > 0; off >>= 1) s += __shfl_down(s, off, 64);
    __shared__ float wsum[4];
    const int lane = threadIdx.x & 63;
    const int wid  = threadIdx.x >> 6;
    if (lane == 0) wsum[wid] = s;
    __syncthreads();
    if (threadIdx.x == 0) {
        atomicAdd(out, wsum[0] + wsum[1] + wsum[2] + wsum[3]);
    }
}

extern "C" void kernel_launch(void* const* d_in, const int* in_sizes, int n_in,
                              void* d_out, int out_size, void* d_ws, size_t ws_size,
                              hipStream_t stream) {
    const float* inp = (const float*)d_in[0];  // [B, N, 3]
    const float* tgt = (const float*)d_in[1];  // [B, M, 3]
    float* out = (float*)d_out;

    const int B = 4, D = 3;
    const int N = in_sizes[0] / (B * D);  // 8192
    const int M = in_sizes[1] / (B * D);  // 8192

    const int MSPLIT = 64;                       // slices (direct path)
    const size_t directNeed =
        (size_t)2 * B * MSPLIT * (size_t)N * sizeof(float);  // 16 MB

    if (N == M && (N % (TPB * 8)) == 0 && (N % MSPLIT) == 0 &&
        ws_size >= directNeed) {
        // ---- direct path: 2 graph nodes ----
        float* wsD = (float*)d_ws;
        dim3 grid(N / (TPB * 8), MSPLIT, 2 * B);   // (4, 64, 8) = 2048 blocks
        chamfer_nn<8, 128, true><<<grid, TPB, 0, stream>>>(
            inp, tgt, wsD, nullptr, nullptr, N, M, B, out);
        reduce_direct<<<dim3(256), 256, 0, stream>>>(
            wsD, N, MSPLIT, B, 1.0f / N, 1.0f / M, out);
    } else {
        // ---- fallback: proven sentinel/atomic path (4 nodes) ----
        unsigned int* min_in  = (unsigned int*)d_ws;
        unsigned int* min_tgt = min_in + (size_t)B * N;
        hipMemsetAsync(d_ws, 0xFF,
                       (size_t)(B * N + B * M) * sizeof(unsigned int), stream);
        hipMemsetAsync(d_out, 0, sizeof(float), stream);
        dim3 grid(N / (TPB * 4), 32, 2 * B);
        chamfer_nn<4, 256, false><<<grid, TPB, 0, stream>>>(
            inp, tgt, nullptr, min_in, min_tgt, N, M, B, out);
        chamfer_reduce<<<dim3(64), 256, 0, stream>>>(
            min_in, B * N, B * (N + M), 1.0f / N, 1.0f / M, out);
    }
}